// Round 4
// baseline (971.387 us; speedup 1.0000x reference)
//
#include <hip/hip_runtime.h>

#define NN 8192
#define NHID 64
#define NCLASS 8
#define NEDGE (NN * 32)   // 262144
#define NSPLIT 8          // gemm1 K-splits
#define DEGCAP 128        // padded slot-CSR capacity (max degree ~55 for this input)
#define GRID 512          // mega-kernel grid (64 M-tiles x 8 K-splits), 2 blocks/CU
#define GTHREADS (GRID * 256)   // 131072

typedef __attribute__((ext_vector_type(8))) short bf16x8_t;
typedef __attribute__((ext_vector_type(4))) float f32x4_t;

__device__ __forceinline__ unsigned short f2bf(float f) {
    unsigned int u = __float_as_uint(f);
    u += 0x7FFF + ((u >> 16) & 1);   // round-to-nearest-even
    return (unsigned short)(u >> 16);
}

// ---------------- grid-wide sense-reversal barrier (device-scope) ----------
// Requires all blocks co-resident (cooperative launch guarantees or fails).
// count must be 0 at kernel start (8-byte memset each launch); gen any value.
__device__ __forceinline__ void gbar(int* count, int* gen) {
    __syncthreads();
    if (threadIdx.x == 0) {
        const int g = __hip_atomic_load(gen, __ATOMIC_RELAXED, __HIP_MEMORY_SCOPE_AGENT);
        __threadfence();   // release this block's prior writes device-wide
        const int arrived =
            __hip_atomic_fetch_add(count, 1, __ATOMIC_ACQ_REL, __HIP_MEMORY_SCOPE_AGENT);
        if (arrived == (int)gridDim.x - 1) {
            __hip_atomic_store(count, 0, __ATOMIC_RELAXED, __HIP_MEMORY_SCOPE_AGENT);
            __hip_atomic_fetch_add(gen, 1, __ATOMIC_ACQ_REL, __HIP_MEMORY_SCOPE_AGENT);
        } else {
            while (__hip_atomic_load(gen, __ATOMIC_ACQUIRE, __HIP_MEMORY_SCOPE_AGENT) == g)
                __builtin_amdgcn_s_sleep(1);
        }
        __threadfence();   // acquire other blocks' writes
    }
    __syncthreads();
}

// ---------------- phase 0: zero cnt/outp + W1 -> bf16 transposed [64][8192]
__device__ __forceinline__ void phase_prep0(int gtid, const float* __restrict__ W1,
                                            unsigned short* __restrict__ w1t,
                                            int* __restrict__ cnt,
                                            float* __restrict__ outp) {
    if (gtid < NN) cnt[gtid] = 0;
    if (gtid < NCLASS) outp[gtid] = 0.f;
#pragma unroll
    for (int j = 0; j < 4; ++j) {
        const int idx = j * GTHREADS + gtid;   // coalesced, covers 64*8192 exactly
        const int n = idx >> 13;
        const int k = idx & (NN - 1);
        w1t[idx] = f2bf(W1[(size_t)k * NHID + n]);
    }
}

// ---------------- slot-CSR build (2 edges/thread), folded into gemm1 phase -
__device__ __forceinline__ void phase_csr(int gtid, const int* __restrict__ row,
                                          const int* __restrict__ col,
                                          const float* __restrict__ val,
                                          int* __restrict__ cnt, int* __restrict__ ccol,
                                          float* __restrict__ cval) {
#pragma unroll
    for (int j = 0; j < 2; ++j) {
        const int e = j * GTHREADS + gtid;   // covers NEDGE exactly
        const int r = row[e];
        const int pos = atomicAdd(&cnt[r], 1);
        if (pos < DEGCAP) {   // cannot overflow for this input; guard vs corruption
            ccol[r * DEGCAP + pos] = col[e];
            cval[r * DEGCAP + pos] = val[e];
        }
    }
}

// ---------------- GEMM1: support1 = x @ W1  (bf16 MFMA, split-K -> partials)
__device__ __forceinline__ void phase_gemm1(const float* __restrict__ x,
                                            const unsigned short* __restrict__ w1t,
                                            float* __restrict__ part,
                                            short (*As)[72], short (*Bs)[72]) {
    const int tid = threadIdx.x;
    const int r0 = (blockIdx.x >> 3) * 128;
    const int ksplit = blockIdx.x & 7;
    const int k0base = ksplit * (NN / NSPLIT);
    const int lane = tid & 63;
    const int wv = tid >> 6;
    const int m16 = lane & 15;
    const int quad = lane >> 4;
    const int c4 = tid & 15;
    const int rA = tid >> 4;
    const int NT = (NN / NSPLIT) / 64;   // 16 K-tiles

    f32x4_t acc[2][4];
#pragma unroll
    for (int i = 0; i < 2; ++i)
#pragma unroll
        for (int j = 0; j < 4; ++j) acc[i][j] = (f32x4_t){0.f, 0.f, 0.f, 0.f};

    float4 areg[8];
    uint4 breg[2];
    {   // prologue: issue loads for tile 0
        const int k0 = k0base;
#pragma unroll
        for (int i = 0; i < 8; ++i)
            areg[i] = *(const float4*)(x + (size_t)(r0 + rA + i * 16) * NN + k0 + c4 * 4);
#pragma unroll
        for (int it = 0; it < 2; ++it) {
            const int idx = tid + it * 256;
            breg[it] = *(const uint4*)(w1t + (size_t)(idx >> 3) * NN + k0 + (idx & 7) * 8);
        }
    }

    for (int kt = 0; kt < NT; ++kt) {
#pragma unroll
        for (int i = 0; i < 8; ++i) {
            const int r = rA + i * 16;
            *(ushort4*)(&As[r][c4 * 4]) = make_ushort4(
                f2bf(areg[i].x), f2bf(areg[i].y), f2bf(areg[i].z), f2bf(areg[i].w));
        }
#pragma unroll
        for (int it = 0; it < 2; ++it) {
            const int idx = tid + it * 256;
            *(uint4*)(&Bs[idx >> 3][(idx & 7) * 8]) = breg[it];
        }
        __syncthreads();
        if (kt + 1 < NT) {   // next tile's loads fly during MFMA phase
            const int k0 = k0base + (kt + 1) * 64;
#pragma unroll
            for (int i = 0; i < 8; ++i)
                areg[i] = *(const float4*)(x + (size_t)(r0 + rA + i * 16) * NN + k0 + c4 * 4);
#pragma unroll
            for (int it = 0; it < 2; ++it) {
                const int idx = tid + it * 256;
                breg[it] = *(const uint4*)(w1t + (size_t)(idx >> 3) * NN + k0 + (idx & 7) * 8);
            }
        }
#pragma unroll
        for (int kk = 0; kk < 64; kk += 32) {
            bf16x8_t af[2], bfr[4];
#pragma unroll
            for (int rt = 0; rt < 2; ++rt)
                af[rt] = *(const bf16x8_t*)(&As[wv * 32 + rt * 16 + m16][kk + quad * 8]);
#pragma unroll
            for (int ct = 0; ct < 4; ++ct)
                bfr[ct] = *(const bf16x8_t*)(&Bs[ct * 16 + m16][kk + quad * 8]);
#pragma unroll
            for (int rt = 0; rt < 2; ++rt)
#pragma unroll
                for (int ct = 0; ct < 4; ++ct)
                    acc[rt][ct] = __builtin_amdgcn_mfma_f32_16x16x32_bf16(
                        af[rt], bfr[ct], acc[rt][ct], 0, 0, 0);
        }
        __syncthreads();
    }
    float* op = part + (size_t)ksplit * (NN * NHID);
#pragma unroll
    for (int rt = 0; rt < 2; ++rt)
#pragma unroll
        for (int ct = 0; ct < 4; ++ct)
#pragma unroll
            for (int reg = 0; reg < 4; ++reg) {
                const int row = r0 + wv * 32 + rt * 16 + quad * 4 + reg;
                const int col = ct * 16 + m16;
                op[(size_t)row * NHID + col] = acc[rt][ct][reg];
            }
}

// ---------------- reduce 8 partials -> support1 (1 float4/thread) ----------
__device__ __forceinline__ void phase_reduce(int gtid, const float* __restrict__ part,
                                             float* __restrict__ sup) {
    const float4* p4 = (const float4*)part;
    float4 a = p4[gtid];
#pragma unroll
    for (int s = 1; s < NSPLIT; ++s) {
        const float4 b = p4[gtid + (size_t)s * (NN * NHID / 4)];
        a.x += b.x; a.y += b.y; a.z += b.z; a.w += b.w;
    }
    ((float4*)sup)[gtid] = a;
}

// ---------------- SpMM #1 fused with GEMM2 (4 rows/wave) -------------------
__device__ __forceinline__ void phase_spmmA(const float* __restrict__ sup,
                                            const int* __restrict__ cnt,
                                            const int* __restrict__ ccol,
                                            const float* __restrict__ cval,
                                            const float* __restrict__ b1,
                                            const float* __restrict__ W2,
                                            float* __restrict__ s2out, float* Ws) {
    for (int i = threadIdx.x; i < NHID * NHID; i += 256) Ws[i] = W2[i];
    __syncthreads();
    const int gw = (blockIdx.x * 256 + threadIdx.x) >> 6;   // 0..2047
    const int lane = threadIdx.x & 63;
    const float bb = b1[lane];
    for (int rr = 0; rr < 4; ++rr) {
        const int wid = gw + rr * 2048;
        const int deg = cnt[wid];
        const int base = wid * DEGCAP;
        float acc = 0.f;
        int i = 0;
        for (; i + 4 <= deg; i += 4) {
            const int4 cc = *(const int4*)(ccol + base + i);
            const float4 vv = *(const float4*)(cval + base + i);
            const float g0 = sup[(size_t)cc.x * NHID + lane];
            const float g1 = sup[(size_t)cc.y * NHID + lane];
            const float g2 = sup[(size_t)cc.z * NHID + lane];
            const float g3 = sup[(size_t)cc.w * NHID + lane];
            acc = fmaf(vv.x, g0, acc);
            acc = fmaf(vv.y, g1, acc);
            acc = fmaf(vv.z, g2, acc);
            acc = fmaf(vv.w, g3, acc);
        }
        for (; i < deg; ++i)
            acc = fmaf(cval[base + i], sup[(size_t)ccol[base + i] * NHID + lane], acc);
        acc = fmaxf(acc + bb, 0.f);   // h1 row lives across the wave
        float o = 0.f;
#pragma unroll
        for (int k = 0; k < NHID; ++k)
            o = fmaf(__shfl(acc, k, 64), Ws[k * NHID + lane], o);
        s2out[(size_t)wid * NHID + lane] = o;
    }
}

// ---------------- SpMM #2 fused with GEMM3 (4 rows/wave) -------------------
__device__ __forceinline__ void phase_spmmB(const float* __restrict__ s2,
                                            const int* __restrict__ cnt,
                                            const int* __restrict__ ccol,
                                            const float* __restrict__ cval,
                                            const float* __restrict__ b2,
                                            const float* __restrict__ W3,
                                            float* __restrict__ s3out) {
    const int gw = (blockIdx.x * 256 + threadIdx.x) >> 6;
    const int lane = threadIdx.x & 63;
    const float4 w3a = *(const float4*)(W3 + lane * NCLASS);
    const float4 w3b = *(const float4*)(W3 + lane * NCLASS + 4);
    const float bb = b2[lane];
    for (int rr = 0; rr < 4; ++rr) {
        const int wid = gw + rr * 2048;
        const int deg = cnt[wid];
        const int base = wid * DEGCAP;
        float acc = 0.f;
        int i = 0;
        for (; i + 4 <= deg; i += 4) {
            const int4 cc = *(const int4*)(ccol + base + i);
            const float4 vv = *(const float4*)(cval + base + i);
            const float g0 = s2[(size_t)cc.x * NHID + lane];
            const float g1 = s2[(size_t)cc.y * NHID + lane];
            const float g2 = s2[(size_t)cc.z * NHID + lane];
            const float g3 = s2[(size_t)cc.w * NHID + lane];
            acc = fmaf(vv.x, g0, acc);
            acc = fmaf(vv.y, g1, acc);
            acc = fmaf(vv.z, g2, acc);
            acc = fmaf(vv.w, g3, acc);
        }
        for (; i < deg; ++i)
            acc = fmaf(cval[base + i], s2[(size_t)ccol[base + i] * NHID + lane], acc);
        acc = fmaxf(acc + bb, 0.f);   // h2[lane]
        float p[8] = {acc * w3a.x, acc * w3a.y, acc * w3a.z, acc * w3a.w,
                      acc * w3b.x, acc * w3b.y, acc * w3b.z, acc * w3b.w};
#pragma unroll
        for (int off = 32; off > 0; off >>= 1)
#pragma unroll
            for (int c = 0; c < 8; ++c) p[c] += __shfl_down(p[c], off, 64);
        if (lane == 0) {
            float4 r0 = {p[0], p[1], p[2], p[3]};
            float4 r1 = {p[4], p[5], p[6], p[7]};
            *(float4*)(s3out + (size_t)wid * NCLASS) = r0;
            *(float4*)(s3out + (size_t)wid * NCLASS + 4) = r1;
        }
    }
}

// ---------------- tail: spmm8 + b3 + log_softmax + final linear ------------
// only blocks [0,256): thread = (row r, class c)
__device__ __forceinline__ void phase_tail(const float* __restrict__ s3,
                                           const int* __restrict__ cnt,
                                           const int* __restrict__ ccol,
                                           const float* __restrict__ cval,
                                           const float* __restrict__ b3,
                                           const float* __restrict__ wlin,
                                           const float* __restrict__ blin,
                                           float* __restrict__ outp, float* cls) {
    const int gid = blockIdx.x * 256 + threadIdx.x;   // < 65536
    const int r = gid >> 3;
    const int c = gid & 7;
    const int deg = cnt[r];
    const int base = r * DEGCAP;
    float acc = 0.f;
    int i = 0;
    for (; i + 4 <= deg; i += 4) {
        const int4 cc = *(const int4*)(ccol + base + i);
        const float4 vv = *(const float4*)(cval + base + i);
        const float g0 = s3[(size_t)cc.x * NCLASS + c];
        const float g1 = s3[(size_t)cc.y * NCLASS + c];
        const float g2 = s3[(size_t)cc.z * NCLASS + c];
        const float g3 = s3[(size_t)cc.w * NCLASS + c];
        acc = fmaf(vv.x, g0, acc);
        acc = fmaf(vv.y, g1, acc);
        acc = fmaf(vv.z, g2, acc);
        acc = fmaf(vv.w, g3, acc);
    }
    for (; i < deg; ++i)
        acc = fmaf(cval[base + i], s3[(size_t)ccol[base + i] * NCLASS + c], acc);
    acc += b3[c];
    float m = acc;
    m = fmaxf(m, __shfl_xor(m, 1, 8));
    m = fmaxf(m, __shfl_xor(m, 2, 8));
    m = fmaxf(m, __shfl_xor(m, 4, 8));
    float sx = expf(acc - m);
    sx += __shfl_xor(sx, 1, 8);
    sx += __shfl_xor(sx, 2, 8);
    sx += __shfl_xor(sx, 4, 8);
    const float ls = acc - m - logf(sx);
    float p = ls * wlin[r];
    p += __shfl_xor(p, 8, 64);
    p += __shfl_xor(p, 16, 64);
    p += __shfl_xor(p, 32, 64);
    const int wv = threadIdx.x >> 6;
    if ((threadIdx.x & 63) < 8) cls[wv * NCLASS + c] = p;
    __syncthreads();
    if (threadIdx.x < NCLASS) {
        float v = cls[threadIdx.x] + cls[NCLASS + threadIdx.x] +
                  cls[2 * NCLASS + threadIdx.x] + cls[3 * NCLASS + threadIdx.x];
        if (blockIdx.x == 0) v += blin[0];
        atomicAdd(&outp[threadIdx.x], v);
    }
}

// ---------------- the cooperative mega-kernel ------------------------------
__global__ __launch_bounds__(256, 2) void mega_kernel(
        const float* x, const int* adj_row, const int* adj_col, const float* adj_val,
        const float* W1, const float* b1, const float* W2, const float* b2,
        const float* W3, const float* b3, const float* wlin, const float* blin,
        float* outp, float* part, float* sup, float* s2, float* s3,
        unsigned short* w1t, int* ccol, float* cval, int* cnt, int* bar) {
    __shared__ union {
        struct { short As[128][72]; short Bs[64][72]; } g;       // 27648 B (gemm1)
        struct { float Ws[NHID * NHID]; float cls[4 * NCLASS]; } s;  // 16512 B
    } u;
    const int gtid = blockIdx.x * 256 + threadIdx.x;
    phase_prep0(gtid, W1, w1t, cnt, outp);
    gbar(bar, bar + 1);
    phase_csr(gtid, adj_row, adj_col, adj_val, cnt, ccol, cval);   // hides under gemm1
    phase_gemm1(x, w1t, part, u.g.As, u.g.Bs);
    gbar(bar, bar + 1);
    phase_reduce(gtid, part, sup);
    gbar(bar, bar + 1);
    phase_spmmA(sup, cnt, ccol, cval, b1, W2, s2, u.s.Ws);
    gbar(bar, bar + 1);
    phase_spmmB(s2, cnt, ccol, cval, b2, W3, s3);
    gbar(bar, bar + 1);
    if (blockIdx.x < 256) phase_tail(s3, cnt, ccol, cval, b3, wlin, blin, outp, u.s.cls);
}

// ---------------- fallback wrappers (no grid barriers -> no deadlock) ------
__global__ __launch_bounds__(256) void k_prep0(const float* W1, unsigned short* w1t,
                                               int* cnt, float* outp) {
    phase_prep0(blockIdx.x * 256 + threadIdx.x, W1, w1t, cnt, outp);
}
__global__ __launch_bounds__(256) void k_csr(const int* row, const int* col, const float* val,
                                             int* cnt, int* ccol, float* cval) {
    phase_csr(blockIdx.x * 256 + threadIdx.x, row, col, val, cnt, ccol, cval);
}
__global__ __launch_bounds__(256, 2) void k_gemm1(const float* x, const unsigned short* w1t,
                                                  float* part) {
    __shared__ short As[128][72];
    __shared__ short Bs[64][72];
    phase_gemm1(x, w1t, part, As, Bs);
}
__global__ __launch_bounds__(256) void k_reduce(const float* part, float* sup) {
    phase_reduce(blockIdx.x * 256 + threadIdx.x, part, sup);
}
__global__ __launch_bounds__(256) void k_spmmA(const float* sup, const int* cnt, const int* ccol,
                                               const float* cval, const float* b1,
                                               const float* W2, float* s2) {
    __shared__ float Ws[NHID * NHID];
    phase_spmmA(sup, cnt, ccol, cval, b1, W2, s2, Ws);
}
__global__ __launch_bounds__(256) void k_spmmB(const float* s2, const int* cnt, const int* ccol,
                                               const float* cval, const float* b2,
                                               const float* W3, float* s3) {
    phase_spmmB(s2, cnt, ccol, cval, b2, W3, s3);
}
__global__ __launch_bounds__(256) void k_tail(const float* s3, const int* cnt, const int* ccol,
                                              const float* cval, const float* b3,
                                              const float* wlin, const float* blin,
                                              float* outp) {
    __shared__ float cls[4 * NCLASS];
    phase_tail(s3, cnt, ccol, cval, b3, wlin, blin, outp, cls);
}

extern "C" void kernel_launch(void* const* d_in, const int* in_sizes, int n_in,
                              void* d_out, int out_size, void* d_ws, size_t ws_size,
                              hipStream_t stream) {
    const float* x       = (const float*)d_in[0];
    const int*   adj_row = (const int*)d_in[1];
    const int*   adj_col = (const int*)d_in[2];
    const float* adj_val = (const float*)d_in[3];
    const float* W1      = (const float*)d_in[4];
    const float* b1      = (const float*)d_in[5];
    const float* W2      = (const float*)d_in[6];
    const float* b2      = (const float*)d_in[7];
    const float* W3      = (const float*)d_in[8];
    const float* b3      = (const float*)d_in[9];
    const float* Wlin    = (const float*)d_in[10];
    const float* blin    = (const float*)d_in[11];
    float* outp = (float*)d_out;

    char* ws = (char*)d_ws;
    float*          part = (float*)ws;                           // 16 MB (split-K partials)
    float*          sup  = (float*)(ws + (16u << 20));           // 2 MB  (support1)
    float*          s2   = (float*)(ws + (18u << 20));           // 2 MB  (support2)
    float*          s3   = (float*)(ws + (20u << 20));           // 256 KB (support3)
    unsigned short* w1t  = (unsigned short*)(ws + (21u << 20));  // 1 MB
    int*            ccol = (int*)(ws + (22u << 20));             // 4 MB  (slot-CSR cols)
    float*          cval = (float*)(ws + (26u << 20));           // 4 MB  (slot-CSR vals)
    int*            cnt  = (int*)(ws + (30u << 20));             // 32 KB (row degrees)
    int*            bar  = (int*)(ws + (31u << 20));             // 8 B   (grid barrier)

    hipMemsetAsync(bar, 0, 2 * sizeof(int), stream);   // count must be 0 (ws is poisoned)

    void* kargs[] = {
        (void*)&x, (void*)&adj_row, (void*)&adj_col, (void*)&adj_val,
        (void*)&W1, (void*)&b1, (void*)&W2, (void*)&b2, (void*)&W3, (void*)&b3,
        (void*)&Wlin, (void*)&blin, (void*)&outp,
        (void*)&part, (void*)&sup, (void*)&s2, (void*)&s3,
        (void*)&w1t, (void*)&ccol, (void*)&cval, (void*)&cnt, (void*)&bar};
    hipError_t err = hipLaunchCooperativeKernel((void*)mega_kernel, dim3(GRID), dim3(256),
                                                kargs, 0, stream);
    if (err != hipSuccess) {
        (void)hipGetLastError();   // clear; fall back to discrete dispatches
        k_prep0<<<GRID, 256, 0, stream>>>(W1, w1t, cnt, outp);
        k_csr<<<GRID, 256, 0, stream>>>(adj_row, adj_col, adj_val, cnt, ccol, cval);
        k_gemm1<<<GRID, 256, 0, stream>>>(x, w1t, part);
        k_reduce<<<GRID, 256, 0, stream>>>(part, sup);
        k_spmmA<<<GRID, 256, 0, stream>>>(sup, cnt, ccol, cval, b1, W2, s2);
        k_spmmB<<<GRID, 256, 0, stream>>>(s2, cnt, ccol, cval, b2, W3, s3);
        k_tail<<<256, 256, 0, stream>>>(s3, cnt, ccol, cval, b3, Wlin, blin, outp);
    }
}

// Round 5
// 574.543 us; speedup vs baseline: 1.6907x; 1.6907x over previous
//
#include <hip/hip_runtime.h>

#define NN 8192
#define NHID 64
#define NCLASS 8
#define NEDGE (NN * 32)   // 262144
#define NSPLIT 8          // gemm1 K-splits
#define DEGCAP 128        // padded slot-CSR capacity (max degree ~55 for this input)

typedef __attribute__((ext_vector_type(8))) short bf16x8_t;
typedef __attribute__((ext_vector_type(4))) float f32x4_t;

__device__ __forceinline__ unsigned short f2bf(float f) {
    unsigned int u = __float_as_uint(f);
    u += 0x7FFF + ((u >> 16) & 1);   // round-to-nearest-even
    return (unsigned short)(u >> 16);
}

// ---------------- fused prep: W1 -> bf16 transposed [64][8192]  +  slot-CSR build
// blocks [0,2048): w1t ; blocks [2048,3072): direct CSR build + tilecnt zeroing
__global__ __launch_bounds__(256) void prep_kernel(const float* __restrict__ W1,
                                                   unsigned short* __restrict__ w1t,
                                                   const int* __restrict__ row,
                                                   const int* __restrict__ col,
                                                   const float* __restrict__ val,
                                                   int* __restrict__ cnt,
                                                   int* __restrict__ ccol,
                                                   float* __restrict__ cval,
                                                   int* __restrict__ tilecnt) {
    const int bid = blockIdx.x;
    if (bid < 2048) {
        const int idx = bid * 256 + threadIdx.x;   // 0 .. 64*8192-1
        const int n = idx >> 13;          // 0..63
        const int k = idx & (NN - 1);     // 0..8191
        w1t[idx] = f2bf(W1[(size_t)k * NHID + n]);  // coalesced writes, L2-cached reads
    } else {
        const int e = (bid - 2048) * 256 + threadIdx.x;   // < NEDGE exactly
        if (e < NN / 128) tilecnt[e] = 0;   // split-K arrival counters (64 M-tiles)
        const int r = row[e];
        const int pos = atomicAdd(&cnt[r], 1);
        if (pos < DEGCAP) {   // cannot overflow for this input; guard vs corruption
            ccol[r * DEGCAP + pos] = col[e];
            cval[r * DEGCAP + pos] = val[e];
        }
    }
}

// ---------------- GEMM1: support1 = x @ W1  (bf16 MFMA, split-K -> partials)
// grid (64, NSPLIT), block 256.  BM=128, BK=64.  Reg-staged double buffer (T14).
// Split-K reduction fused via last-arriving-block pattern (device-scope
// atomics + fences per G16; NO spin loop — 63 blocks exit, the last reduces).
__global__ __launch_bounds__(256, 2) void gemm1_kernel(const float* __restrict__ x,
                                                       const unsigned short* __restrict__ w1t,
                                                       float* __restrict__ part,
                                                       int* __restrict__ tilecnt,
                                                       float* __restrict__ sup) {
    __shared__ short As[128][72];   // row-major tile, padded (144B rows, 16B aligned)
    __shared__ short Bs[64][72];    // Bs[n][k]
    __shared__ int lastflag;
    const int tid = threadIdx.x;
    const int r0 = blockIdx.x * 128;
    const int k0base = blockIdx.y * (NN / NSPLIT);
    const int lane = tid & 63;
    const int wv = tid >> 6;
    const int m16 = lane & 15;
    const int quad = lane >> 4;
    const int c4 = tid & 15;
    const int rA = tid >> 4;
    const int NT = (NN / NSPLIT) / 64;   // 16 K-tiles

    f32x4_t acc[2][4];
#pragma unroll
    for (int i = 0; i < 2; ++i)
#pragma unroll
        for (int j = 0; j < 4; ++j) acc[i][j] = (f32x4_t){0.f, 0.f, 0.f, 0.f};

    float4 areg[8];
    uint4 breg[2];
    {   // prologue: issue loads for tile 0
        const int k0 = k0base;
#pragma unroll
        for (int i = 0; i < 8; ++i)
            areg[i] = *(const float4*)(x + (size_t)(r0 + rA + i * 16) * NN + k0 + c4 * 4);
#pragma unroll
        for (int it = 0; it < 2; ++it) {
            const int idx = tid + it * 256;
            breg[it] = *(const uint4*)(w1t + (size_t)(idx >> 3) * NN + k0 + (idx & 7) * 8);
        }
    }

    for (int kt = 0; kt < NT; ++kt) {
        // drain staged regs to LDS (implicit vmcnt wait happens here)
#pragma unroll
        for (int i = 0; i < 8; ++i) {
            const int r = rA + i * 16;
            *(ushort4*)(&As[r][c4 * 4]) = make_ushort4(
                f2bf(areg[i].x), f2bf(areg[i].y), f2bf(areg[i].z), f2bf(areg[i].w));
        }
#pragma unroll
        for (int it = 0; it < 2; ++it) {
            const int idx = tid + it * 256;
            *(uint4*)(&Bs[idx >> 3][(idx & 7) * 8]) = breg[it];
        }
        __syncthreads();
        if (kt + 1 < NT) {   // next tile's loads fly during the MFMA phase
            const int k0 = k0base + (kt + 1) * 64;
#pragma unroll
            for (int i = 0; i < 8; ++i)
                areg[i] = *(const float4*)(x + (size_t)(r0 + rA + i * 16) * NN + k0 + c4 * 4);
#pragma unroll
            for (int it = 0; it < 2; ++it) {
                const int idx = tid + it * 256;
                breg[it] = *(const uint4*)(w1t + (size_t)(idx >> 3) * NN + k0 + (idx & 7) * 8);
            }
        }
#pragma unroll
        for (int kk = 0; kk < 64; kk += 32) {
            bf16x8_t af[2], bfr[4];
#pragma unroll
            for (int rt = 0; rt < 2; ++rt)
                af[rt] = *(const bf16x8_t*)(&As[wv * 32 + rt * 16 + m16][kk + quad * 8]);
#pragma unroll
            for (int ct = 0; ct < 4; ++ct)
                bfr[ct] = *(const bf16x8_t*)(&Bs[ct * 16 + m16][kk + quad * 8]);
#pragma unroll
            for (int rt = 0; rt < 2; ++rt)
#pragma unroll
                for (int ct = 0; ct < 4; ++ct)
                    acc[rt][ct] = __builtin_amdgcn_mfma_f32_16x16x32_bf16(
                        af[rt], bfr[ct], acc[rt][ct], 0, 0, 0);
        }
        __syncthreads();
    }
    // epilogue: plain stores into this split's private partial buffer
    float* op = part + (size_t)blockIdx.y * (NN * NHID);
#pragma unroll
    for (int rt = 0; rt < 2; ++rt)
#pragma unroll
        for (int ct = 0; ct < 4; ++ct)
#pragma unroll
            for (int reg = 0; reg < 4; ++reg) {
                const int row = r0 + wv * 32 + rt * 16 + quad * 4 + reg;
                const int col = ct * 16 + m16;
                op[(size_t)row * NHID + col] = acc[rt][ct][reg];
            }
    // ---- fused split-K reduction: last block for this M-tile sums partials
    __threadfence();   // release: write back this block's partial stores (L2 wb)
    if (tid == 0) {
        const int prev = __hip_atomic_fetch_add(&tilecnt[blockIdx.x], 1,
                                                __ATOMIC_ACQ_REL,
                                                __HIP_MEMORY_SCOPE_AGENT);
        lastflag = (prev == NSPLIT - 1);
    }
    __syncthreads();
    if (lastflag) {
        __threadfence();   // acquire: invalidate stale L2 lines before reading
        const float4* p4 = (const float4*)part;
        float4* sup4 = (float4*)sup;
        const int base = (r0 * NHID) / 4;   // this M-tile's rows: 2048 float4
#pragma unroll
        for (int j = 0; j < 8; ++j) {
            const int off = base + j * 256 + tid;
            float4 a = p4[off];
#pragma unroll
            for (int s = 1; s < NSPLIT; ++s) {
                const float4 b = p4[off + (size_t)s * (NN * NHID / 4)];
                a.x += b.x; a.y += b.y; a.z += b.z; a.w += b.w;
            }
            sup4[off] = a;
        }
    }
}

// ---------------- SpMM #1 fused with GEMM2 ---------------------------------
// one wave per dest row (lane = feature): h1 = relu(spmm(sup)+b1) held in regs,
// then support2[lane] = sum_k h1[k] * W2[k][lane] via shfl-FMA (W2 in LDS).
__global__ __launch_bounds__(256) void spmmA_kernel(const float* __restrict__ sup,
                                                    const int* __restrict__ cnt,
                                                    const int* __restrict__ ccol,
                                                    const float* __restrict__ cval,
                                                    const float* __restrict__ b1,
                                                    const float* __restrict__ W2,
                                                    float* __restrict__ s2out) {
    __shared__ float Ws[NHID * NHID];
    for (int i = threadIdx.x; i < NHID * NHID; i += 256) Ws[i] = W2[i];
    __syncthreads();
    const int wid = (blockIdx.x * 256 + threadIdx.x) >> 6;   // dest row
    const int lane = threadIdx.x & 63;
    const int deg = cnt[wid];
    const int base = wid * DEGCAP;
    float acc = 0.f;
    int i = 0;
    for (; i + 4 <= deg; i += 4) {           // 4 gathers in flight
        const int4 cc = *(const int4*)(ccol + base + i);
        const float4 vv = *(const float4*)(cval + base + i);
        const float g0 = sup[(size_t)cc.x * NHID + lane];
        const float g1 = sup[(size_t)cc.y * NHID + lane];
        const float g2 = sup[(size_t)cc.z * NHID + lane];
        const float g3 = sup[(size_t)cc.w * NHID + lane];
        acc = fmaf(vv.x, g0, acc);
        acc = fmaf(vv.y, g1, acc);
        acc = fmaf(vv.z, g2, acc);
        acc = fmaf(vv.w, g3, acc);
    }
    for (; i < deg; ++i)
        acc = fmaf(cval[base + i], sup[(size_t)ccol[base + i] * NHID + lane], acc);
    acc = fmaxf(acc + b1[lane], 0.f);        // h1 row lives across the wave
    float o = 0.f;
#pragma unroll
    for (int k = 0; k < NHID; ++k)
        o = fmaf(__shfl(acc, k, 64), Ws[k * NHID + lane], o);
    s2out[(size_t)wid * NHID + lane] = o;    // support2 row, coalesced
}

// ---------------- SpMM #2 fused with GEMM3 ---------------------------------
// h2 = relu(spmm(s2)+b2) in regs; support3[c] = sum_k h2[k]*W3[k][c] via
// per-lane W3 row (8 VGPRs) + wave tree-reduce of 8 partials.
__global__ __launch_bounds__(256) void spmmB_kernel(const float* __restrict__ s2,
                                                    const int* __restrict__ cnt,
                                                    const int* __restrict__ ccol,
                                                    const float* __restrict__ cval,
                                                    const float* __restrict__ b2,
                                                    const float* __restrict__ W3,
                                                    float* __restrict__ s3out) {
    const int wid = (blockIdx.x * 256 + threadIdx.x) >> 6;
    const int lane = threadIdx.x & 63;
    const float4 w3a = *(const float4*)(W3 + lane * NCLASS);
    const float4 w3b = *(const float4*)(W3 + lane * NCLASS + 4);
    const int deg = cnt[wid];
    const int base = wid * DEGCAP;
    float acc = 0.f;
    int i = 0;
    for (; i + 4 <= deg; i += 4) {
        const int4 cc = *(const int4*)(ccol + base + i);
        const float4 vv = *(const float4*)(cval + base + i);
        const float g0 = s2[(size_t)cc.x * NHID + lane];
        const float g1 = s2[(size_t)cc.y * NHID + lane];
        const float g2 = s2[(size_t)cc.z * NHID + lane];
        const float g3 = s2[(size_t)cc.w * NHID + lane];
        acc = fmaf(vv.x, g0, acc);
        acc = fmaf(vv.y, g1, acc);
        acc = fmaf(vv.z, g2, acc);
        acc = fmaf(vv.w, g3, acc);
    }
    for (; i < deg; ++i)
        acc = fmaf(cval[base + i], s2[(size_t)ccol[base + i] * NHID + lane], acc);
    acc = fmaxf(acc + b2[lane], 0.f);        // h2[lane]
    float p[8] = {acc * w3a.x, acc * w3a.y, acc * w3a.z, acc * w3a.w,
                  acc * w3b.x, acc * w3b.y, acc * w3b.z, acc * w3b.w};
#pragma unroll
    for (int off = 32; off > 0; off >>= 1)
#pragma unroll
        for (int c = 0; c < 8; ++c) p[c] += __shfl_down(p[c], off, 64);
    if (lane == 0) {
        float4 r0 = {p[0], p[1], p[2], p[3]};
        float4 r1 = {p[4], p[5], p[6], p[7]};
        *(float4*)(s3out + (size_t)wid * NCLASS) = r0;
        *(float4*)(s3out + (size_t)wid * NCLASS + 4) = r1;
    }
}

// ---------------- tail: spmm8 + b3 + log_softmax + final linear ------------
// thread = (row r, class c); 8-lane-group shuffles do the softmax row ops.
__global__ __launch_bounds__(256) void tail_kernel(const float* __restrict__ s3,
                                                   const int* __restrict__ cnt,
                                                   const int* __restrict__ ccol,
                                                   const float* __restrict__ cval,
                                                   const float* __restrict__ b3,
                                                   const float* __restrict__ wlin,
                                                   const float* __restrict__ blin,
                                                   float* __restrict__ outp) {
    __shared__ float cls[4 * NCLASS];
    const int gid = blockIdx.x * 256 + threadIdx.x;
    const int r = gid >> 3;
    const int c = gid & 7;
    const int deg = cnt[r];
    const int base = r * DEGCAP;
    float acc = 0.f;
    int i = 0;
    for (; i + 4 <= deg; i += 4) {
        const int4 cc = *(const int4*)(ccol + base + i);
        const float4 vv = *(const float4*)(cval + base + i);
        const float g0 = s3[(size_t)cc.x * NCLASS + c];
        const float g1 = s3[(size_t)cc.y * NCLASS + c];
        const float g2 = s3[(size_t)cc.z * NCLASS + c];
        const float g3 = s3[(size_t)cc.w * NCLASS + c];
        acc = fmaf(vv.x, g0, acc);
        acc = fmaf(vv.y, g1, acc);
        acc = fmaf(vv.z, g2, acc);
        acc = fmaf(vv.w, g3, acc);
    }
    for (; i < deg; ++i)
        acc = fmaf(cval[base + i], s3[(size_t)ccol[base + i] * NCLASS + c], acc);
    acc += b3[c];
    // log_softmax across the 8-lane group
    float m = acc;
    m = fmaxf(m, __shfl_xor(m, 1, 8));
    m = fmaxf(m, __shfl_xor(m, 2, 8));
    m = fmaxf(m, __shfl_xor(m, 4, 8));
    float sx = expf(acc - m);
    sx += __shfl_xor(sx, 1, 8);
    sx += __shfl_xor(sx, 2, 8);
    sx += __shfl_xor(sx, 4, 8);
    const float ls = acc - m - logf(sx);
    // weighted class sums: reduce same-class lanes (stride 8) across the wave
    float p = ls * wlin[r];
    p += __shfl_xor(p, 8, 64);
    p += __shfl_xor(p, 16, 64);
    p += __shfl_xor(p, 32, 64);
    const int wv = threadIdx.x >> 6;
    if ((threadIdx.x & 63) < 8) cls[wv * NCLASS + c] = p;
    __syncthreads();
    if (threadIdx.x < NCLASS) {
        float v = cls[threadIdx.x] + cls[NCLASS + threadIdx.x] +
                  cls[2 * NCLASS + threadIdx.x] + cls[3 * NCLASS + threadIdx.x];
        if (blockIdx.x == 0) v += blin[0];    // fold bias in exactly once
        atomicAdd(&outp[threadIdx.x], v);
    }
}

extern "C" void kernel_launch(void* const* d_in, const int* in_sizes, int n_in,
                              void* d_out, int out_size, void* d_ws, size_t ws_size,
                              hipStream_t stream) {
    const float* x       = (const float*)d_in[0];
    const int*   adj_row = (const int*)d_in[1];
    const int*   adj_col = (const int*)d_in[2];
    const float* adj_val = (const float*)d_in[3];
    const float* W1      = (const float*)d_in[4];
    const float* b1      = (const float*)d_in[5];
    const float* W2      = (const float*)d_in[6];
    const float* b2      = (const float*)d_in[7];
    const float* W3      = (const float*)d_in[8];
    const float* b3      = (const float*)d_in[9];
    const float* Wlin    = (const float*)d_in[10];
    const float* blin    = (const float*)d_in[11];
    float* outp = (float*)d_out;

    char* ws = (char*)d_ws;
    float*          part    = (float*)ws;                           // 16 MB (split-K partials)
    float*          sup     = (float*)(ws + (16u << 20));           // 2 MB  (support1)
    float*          s2      = (float*)(ws + (18u << 20));           // 2 MB  (support2)
    float*          s3      = (float*)(ws + (20u << 20));           // 256 KB (support3)
    unsigned short* w1t     = (unsigned short*)(ws + (21u << 20));  // 1 MB
    int*            ccol    = (int*)(ws + (22u << 20));             // 4 MB  (slot-CSR cols)
    float*          cval    = (float*)(ws + (26u << 20));           // 4 MB  (slot-CSR vals)
    int*            cnt     = (int*)(ws + (30u << 20));             // 32 KB (row degrees)
    int*            tilecnt = (int*)(ws + (31u << 20));             // 256 B (split-K arrival)

    hipMemsetAsync(cnt, 0, (size_t)NN * sizeof(int), stream);
    hipMemsetAsync(outp, 0, NCLASS * sizeof(float), stream);

    prep_kernel<<<3072, 256, 0, stream>>>(W1, w1t, adj_row, adj_col, adj_val,
                                          cnt, ccol, cval, tilecnt);
    gemm1_kernel<<<dim3(NN / 128, NSPLIT), 256, 0, stream>>>(x, w1t, part, tilecnt, sup);
    spmmA_kernel<<<(NN * 64) / 256, 256, 0, stream>>>(sup, cnt, ccol, cval, b1, W2, s2);
    spmmB_kernel<<<(NN * 64) / 256, 256, 0, stream>>>(s2, cnt, ccol, cval, b2, W3, s3);
    tail_kernel<<<(NN * 8) / 256, 256, 0, stream>>>(s3, cnt, ccol, cval, b3,
                                                    Wlin, blin, outp);
}

// Round 6
// 473.151 us; speedup vs baseline: 2.0530x; 1.2143x over previous
//
#include <hip/hip_runtime.h>

#define NN 8192
#define NHID 64
#define NCLASS 8
#define NEDGE (NN * 32)   // 262144
#define NSPLIT 16         // gemm1 K-splits (512-wide slabs)
#define DEGCAP 128        // padded slot-CSR capacity (max degree ~55 for this input)

typedef __attribute__((ext_vector_type(8))) short bf16x8_t;
typedef __attribute__((ext_vector_type(4))) float f32x4_t;

__device__ __forceinline__ unsigned short f2bf(float f) {
    unsigned int u = __float_as_uint(f);
    u += 0x7FFF + ((u >> 16) & 1);   // round-to-nearest-even
    return (unsigned short)(u >> 16);
}

__device__ __forceinline__ bf16x8_t pack8(const float4 lo, const float4 hi) {
    bf16x8_t r;
    r[0] = (short)f2bf(lo.x); r[1] = (short)f2bf(lo.y);
    r[2] = (short)f2bf(lo.z); r[3] = (short)f2bf(lo.w);
    r[4] = (short)f2bf(hi.x); r[5] = (short)f2bf(hi.y);
    r[6] = (short)f2bf(hi.z); r[7] = (short)f2bf(hi.w);
    return r;
}

__device__ __forceinline__ bf16x8_t as_bf8(const uint4 u) {
    union { uint4 u; bf16x8_t v; } c;
    c.u = u;
    return c.v;
}

// ---------------- fused prep: W1 -> bf16 transposed [64][8192]  +  slot-CSR build
// blocks [0,2048): w1t ; blocks [2048,3072): direct CSR build (no scan/scatter)
__global__ __launch_bounds__(256) void prep_kernel(const float* __restrict__ W1,
                                                   unsigned short* __restrict__ w1t,
                                                   const int* __restrict__ row,
                                                   const int* __restrict__ col,
                                                   const float* __restrict__ val,
                                                   int* __restrict__ cnt,
                                                   int* __restrict__ ccol,
                                                   float* __restrict__ cval) {
    const int bid = blockIdx.x;
    if (bid < 2048) {
        const int idx = bid * 256 + threadIdx.x;   // 0 .. 64*8192-1
        const int n = idx >> 13;          // 0..63
        const int k = idx & (NN - 1);     // 0..8191
        w1t[idx] = f2bf(W1[(size_t)k * NHID + n]);  // coalesced writes, L2-cached reads
    } else {
        const int e = (bid - 2048) * 256 + threadIdx.x;   // < NEDGE exactly
        const int r = row[e];
        const int pos = atomicAdd(&cnt[r], 1);
        if (pos < DEGCAP) {   // cannot overflow for this input; guard vs corruption
            ccol[r * DEGCAP + pos] = col[e];
            cval[r * DEGCAP + pos] = val[e];
        }
    }
}

// ---------------- GEMM1: support1 = x @ W1  (bf16 MFMA, split-K -> partials)
// grid (64, NSPLIT), block 256 = 4 waves; each wave owns 32 rows.
// LDS-FREE: each A element is consumed by exactly one wave exactly once, so
// LDS staging was pure overhead (plus 2 barriers/K-tile + bank conflicts).
// A fragments load straight from x (lane: 8 consecutive fp32 -> f2bf);
// B fragments straight from w1t (16B/lane, L2-resident; 4x redundancy is
// ~256 MB of L2 traffic ~= 7 us aggregate). No barriers -> waves independent,
// 1-deep register prefetch; NSPLIT=16 gives 1024 blocks = 4 waves/SIMD.
__global__ __launch_bounds__(256, 4) void gemm1_kernel(const float* __restrict__ x,
                                                       const unsigned short* __restrict__ w1t,
                                                       float* __restrict__ part) {
    const int tid = threadIdx.x;
    const int r0 = blockIdx.x * 128;
    const int k0 = blockIdx.y * (NN / NSPLIT);   // 512-wide K slab
    const int lane = tid & 63;
    const int wv = tid >> 6;
    const int m16 = lane & 15;
    const int quad = lane >> 4;
    const int NT = (NN / NSPLIT) / 32;   // 16 K-steps of 32

    // per-lane source pointers (fragment layout == previous LDS-tile reads)
    const float* xr0 = x + (size_t)(r0 + wv * 32 + m16) * NN + k0 + quad * 8;  // rt=0 rows
    const float* xr1 = xr0 + (size_t)16 * NN;                                   // rt=1 rows
    const unsigned short* bp = w1t + (size_t)m16 * NN + k0 + quad * 8;          // + ct*16*NN

    f32x4_t acc[2][4];
#pragma unroll
    for (int i = 0; i < 2; ++i)
#pragma unroll
        for (int j = 0; j < 4; ++j) acc[i][j] = (f32x4_t){0.f, 0.f, 0.f, 0.f};

    // prefetch tile 0
    float4 a0l = *(const float4*)(xr0);
    float4 a0h = *(const float4*)(xr0 + 4);
    float4 a1l = *(const float4*)(xr1);
    float4 a1h = *(const float4*)(xr1 + 4);
    uint4 b0 = *(const uint4*)(bp);
    uint4 b1 = *(const uint4*)(bp + (size_t)16 * NN);
    uint4 b2 = *(const uint4*)(bp + (size_t)32 * NN);
    uint4 b3 = *(const uint4*)(bp + (size_t)48 * NN);

#pragma unroll 2
    for (int kt = 0; kt < NT; ++kt) {
        // convert/copy current tile out of the prefetch registers
        const bf16x8_t af0 = pack8(a0l, a0h);
        const bf16x8_t af1 = pack8(a1l, a1h);
        const bf16x8_t bf0 = as_bf8(b0);
        const bf16x8_t bf1 = as_bf8(b1);
        const bf16x8_t bf2 = as_bf8(b2);
        const bf16x8_t bf3 = as_bf8(b3);
        // issue next tile's loads; they fly under the MFMAs (no barriers)
        if (kt + 1 < NT) {
            const int o = (kt + 1) * 32;
            a0l = *(const float4*)(xr0 + o);
            a0h = *(const float4*)(xr0 + o + 4);
            a1l = *(const float4*)(xr1 + o);
            a1h = *(const float4*)(xr1 + o + 4);
            b0 = *(const uint4*)(bp + o);
            b1 = *(const uint4*)(bp + o + (size_t)16 * NN);
            b2 = *(const uint4*)(bp + o + (size_t)32 * NN);
            b3 = *(const uint4*)(bp + o + (size_t)48 * NN);
        }
        acc[0][0] = __builtin_amdgcn_mfma_f32_16x16x32_bf16(af0, bf0, acc[0][0], 0, 0, 0);
        acc[0][1] = __builtin_amdgcn_mfma_f32_16x16x32_bf16(af0, bf1, acc[0][1], 0, 0, 0);
        acc[0][2] = __builtin_amdgcn_mfma_f32_16x16x32_bf16(af0, bf2, acc[0][2], 0, 0, 0);
        acc[0][3] = __builtin_amdgcn_mfma_f32_16x16x32_bf16(af0, bf3, acc[0][3], 0, 0, 0);
        acc[1][0] = __builtin_amdgcn_mfma_f32_16x16x32_bf16(af1, bf0, acc[1][0], 0, 0, 0);
        acc[1][1] = __builtin_amdgcn_mfma_f32_16x16x32_bf16(af1, bf1, acc[1][1], 0, 0, 0);
        acc[1][2] = __builtin_amdgcn_mfma_f32_16x16x32_bf16(af1, bf2, acc[1][2], 0, 0, 0);
        acc[1][3] = __builtin_amdgcn_mfma_f32_16x16x32_bf16(af1, bf3, acc[1][3], 0, 0, 0);
    }
    // epilogue: plain stores into this split's private partial buffer
    // C/D layout: col = ct*16 + m16, row = quad*4 + reg (per 16x16 fragment)
    float* op = part + (size_t)blockIdx.y * (NN * NHID);
#pragma unroll
    for (int rt = 0; rt < 2; ++rt)
#pragma unroll
        for (int ct = 0; ct < 4; ++ct)
#pragma unroll
            for (int reg = 0; reg < 4; ++reg) {
                const int row = r0 + wv * 32 + rt * 16 + quad * 4 + reg;
                const int col = ct * 16 + m16;
                op[(size_t)row * NHID + col] = acc[rt][ct][reg];
            }
}

// ---------------- reduce 16 partials -> support1 ---------------------------
__global__ __launch_bounds__(256) void reduce_kernel(const float* __restrict__ part,
                                                     float* __restrict__ sup) {
    const int i = blockIdx.x * 256 + threadIdx.x;   // float4 index, < NN*NHID/4
    const float4* p4 = (const float4*)part;
    float4 a = p4[i];
#pragma unroll
    for (int s = 1; s < NSPLIT; ++s) {
        const float4 b = p4[i + (size_t)s * (NN * NHID / 4)];
        a.x += b.x; a.y += b.y; a.z += b.z; a.w += b.w;
    }
    ((float4*)sup)[i] = a;
}

// ---------------- SpMM #1 fused with GEMM2 ---------------------------------
// one wave per dest row (lane = feature): h1 = relu(spmm(sup)+b1) held in regs,
// then support2[lane] = sum_k h1[k] * W2[k][lane] via shfl-FMA (W2 in LDS).
__global__ __launch_bounds__(256) void spmmA_kernel(const float* __restrict__ sup,
                                                    const int* __restrict__ cnt,
                                                    const int* __restrict__ ccol,
                                                    const float* __restrict__ cval,
                                                    const float* __restrict__ b1,
                                                    const float* __restrict__ W2,
                                                    float* __restrict__ s2out) {
    __shared__ float Ws[NHID * NHID];
    for (int i = threadIdx.x; i < NHID * NHID; i += 256) Ws[i] = W2[i];
    __syncthreads();
    const int wid = (blockIdx.x * 256 + threadIdx.x) >> 6;   // dest row
    const int lane = threadIdx.x & 63;
    const int deg = cnt[wid];
    const int base = wid * DEGCAP;
    float acc = 0.f;
    int i = 0;
    for (; i + 4 <= deg; i += 4) {           // 4 gathers in flight
        const int4 cc = *(const int4*)(ccol + base + i);
        const float4 vv = *(const float4*)(cval + base + i);
        const float g0 = sup[(size_t)cc.x * NHID + lane];
        const float g1 = sup[(size_t)cc.y * NHID + lane];
        const float g2 = sup[(size_t)cc.z * NHID + lane];
        const float g3 = sup[(size_t)cc.w * NHID + lane];
        acc = fmaf(vv.x, g0, acc);
        acc = fmaf(vv.y, g1, acc);
        acc = fmaf(vv.z, g2, acc);
        acc = fmaf(vv.w, g3, acc);
    }
    for (; i < deg; ++i)
        acc = fmaf(cval[base + i], sup[(size_t)ccol[base + i] * NHID + lane], acc);
    acc = fmaxf(acc + b1[lane], 0.f);        // h1 row lives across the wave
    float o = 0.f;
#pragma unroll
    for (int k = 0; k < NHID; ++k)
        o = fmaf(__shfl(acc, k, 64), Ws[k * NHID + lane], o);
    s2out[(size_t)wid * NHID + lane] = o;    // support2 row, coalesced
}

// ---------------- SpMM #2 fused with GEMM3 ---------------------------------
// h2 = relu(spmm(s2)+b2) in regs; support3[c] = sum_k h2[k]*W3[k][c] via
// per-lane W3 row (8 VGPRs) + wave tree-reduce of 8 partials.
__global__ __launch_bounds__(256) void spmmB_kernel(const float* __restrict__ s2,
                                                    const int* __restrict__ cnt,
                                                    const int* __restrict__ ccol,
                                                    const float* __restrict__ cval,
                                                    const float* __restrict__ b2,
                                                    const float* __restrict__ W3,
                                                    float* __restrict__ s3out) {
    const int wid = (blockIdx.x * 256 + threadIdx.x) >> 6;
    const int lane = threadIdx.x & 63;
    const float4 w3a = *(const float4*)(W3 + lane * NCLASS);
    const float4 w3b = *(const float4*)(W3 + lane * NCLASS + 4);
    const int deg = cnt[wid];
    const int base = wid * DEGCAP;
    float acc = 0.f;
    int i = 0;
    for (; i + 4 <= deg; i += 4) {
        const int4 cc = *(const int4*)(ccol + base + i);
        const float4 vv = *(const float4*)(cval + base + i);
        const float g0 = s2[(size_t)cc.x * NHID + lane];
        const float g1 = s2[(size_t)cc.y * NHID + lane];
        const float g2 = s2[(size_t)cc.z * NHID + lane];
        const float g3 = s2[(size_t)cc.w * NHID + lane];
        acc = fmaf(vv.x, g0, acc);
        acc = fmaf(vv.y, g1, acc);
        acc = fmaf(vv.z, g2, acc);
        acc = fmaf(vv.w, g3, acc);
    }
    for (; i < deg; ++i)
        acc = fmaf(cval[base + i], s2[(size_t)ccol[base + i] * NHID + lane], acc);
    acc = fmaxf(acc + b2[lane], 0.f);        // h2[lane]
    float p[8] = {acc * w3a.x, acc * w3a.y, acc * w3a.z, acc * w3a.w,
                  acc * w3b.x, acc * w3b.y, acc * w3b.z, acc * w3b.w};
#pragma unroll
    for (int off = 32; off > 0; off >>= 1)
#pragma unroll
        for (int c = 0; c < 8; ++c) p[c] += __shfl_down(p[c], off, 64);
    if (lane == 0) {
        float4 r0 = {p[0], p[1], p[2], p[3]};
        float4 r1 = {p[4], p[5], p[6], p[7]};
        *(float4*)(s3out + (size_t)wid * NCLASS) = r0;
        *(float4*)(s3out + (size_t)wid * NCLASS + 4) = r1;
    }
}

// ---------------- tail: spmm8 + b3 + log_softmax + final linear ------------
// thread = (row r, class c); 8-lane-group shuffles do the softmax row ops.
__global__ __launch_bounds__(256) void tail_kernel(const float* __restrict__ s3,
                                                   const int* __restrict__ cnt,
                                                   const int* __restrict__ ccol,
                                                   const float* __restrict__ cval,
                                                   const float* __restrict__ b3,
                                                   const float* __restrict__ wlin,
                                                   const float* __restrict__ blin,
                                                   float* __restrict__ outp) {
    __shared__ float cls[4 * NCLASS];
    const int gid = blockIdx.x * 256 + threadIdx.x;
    const int r = gid >> 3;
    const int c = gid & 7;
    const int deg = cnt[r];
    const int base = r * DEGCAP;
    float acc = 0.f;
    int i = 0;
    for (; i + 4 <= deg; i += 4) {
        const int4 cc = *(const int4*)(ccol + base + i);
        const float4 vv = *(const float4*)(cval + base + i);
        const float g0 = s3[(size_t)cc.x * NCLASS + c];
        const float g1 = s3[(size_t)cc.y * NCLASS + c];
        const float g2 = s3[(size_t)cc.z * NCLASS + c];
        const float g3 = s3[(size_t)cc.w * NCLASS + c];
        acc = fmaf(vv.x, g0, acc);
        acc = fmaf(vv.y, g1, acc);
        acc = fmaf(vv.z, g2, acc);
        acc = fmaf(vv.w, g3, acc);
    }
    for (; i < deg; ++i)
        acc = fmaf(cval[base + i], s3[(size_t)ccol[base + i] * NCLASS + c], acc);
    acc += b3[c];
    // log_softmax across the 8-lane group
    float m = acc;
    m = fmaxf(m, __shfl_xor(m, 1, 8));
    m = fmaxf(m, __shfl_xor(m, 2, 8));
    m = fmaxf(m, __shfl_xor(m, 4, 8));
    float sx = expf(acc - m);
    sx += __shfl_xor(sx, 1, 8);
    sx += __shfl_xor(sx, 2, 8);
    sx += __shfl_xor(sx, 4, 8);
    const float ls = acc - m - logf(sx);
    // weighted class sums: reduce same-class lanes (stride 8) across the wave
    float p = ls * wlin[r];
    p += __shfl_xor(p, 8, 64);
    p += __shfl_xor(p, 16, 64);
    p += __shfl_xor(p, 32, 64);
    const int wv = threadIdx.x >> 6;
    if ((threadIdx.x & 63) < 8) cls[wv * NCLASS + c] = p;
    __syncthreads();
    if (threadIdx.x < NCLASS) {
        float v = cls[threadIdx.x] + cls[NCLASS + threadIdx.x] +
                  cls[2 * NCLASS + threadIdx.x] + cls[3 * NCLASS + threadIdx.x];
        if (blockIdx.x == 0) v += blin[0];    // fold bias in exactly once
        atomicAdd(&outp[threadIdx.x], v);
    }
}

extern "C" void kernel_launch(void* const* d_in, const int* in_sizes, int n_in,
                              void* d_out, int out_size, void* d_ws, size_t ws_size,
                              hipStream_t stream) {
    const float* x       = (const float*)d_in[0];
    const int*   adj_row = (const int*)d_in[1];
    const int*   adj_col = (const int*)d_in[2];
    const float* adj_val = (const float*)d_in[3];
    const float* W1      = (const float*)d_in[4];
    const float* b1      = (const float*)d_in[5];
    const float* W2      = (const float*)d_in[6];
    const float* b2      = (const float*)d_in[7];
    const float* W3      = (const float*)d_in[8];
    const float* b3      = (const float*)d_in[9];
    const float* Wlin    = (const float*)d_in[10];
    const float* blin    = (const float*)d_in[11];
    float* outp = (float*)d_out;

    char* ws = (char*)d_ws;
    float*          part = (float*)ws;                           // 32 MB (split-K partials)
    float*          sup  = (float*)(ws + (32u << 20));           // 2 MB  (support1)
    float*          s2   = (float*)(ws + (34u << 20));           // 2 MB  (support2)
    float*          s3   = (float*)(ws + (36u << 20));           // 256 KB (support3)
    unsigned short* w1t  = (unsigned short*)(ws + (37u << 20));  // 1 MB
    int*            ccol = (int*)(ws + (38u << 20));             // 4 MB  (slot-CSR cols)
    float*          cval = (float*)(ws + (42u << 20));           // 4 MB  (slot-CSR vals)
    int*            cnt  = (int*)(ws + (46u << 20));             // 32 KB (row degrees)

    hipMemsetAsync(cnt, 0, (size_t)NN * sizeof(int), stream);
    hipMemsetAsync(outp, 0, NCLASS * sizeof(float), stream);

    prep_kernel<<<3072, 256, 0, stream>>>(W1, w1t, adj_row, adj_col, adj_val,
                                          cnt, ccol, cval);
    gemm1_kernel<<<dim3(NN / 128, NSPLIT), 256, 0, stream>>>(x, w1t, part);
    reduce_kernel<<<(NN * NHID / 4) / 256, 256, 0, stream>>>(part, sup);
    spmmA_kernel<<<(NN * 64) / 256, 256, 0, stream>>>(sup, cnt, ccol, cval, b1, W2, s2);
    spmmB_kernel<<<(NN * 64) / 256, 256, 0, stream>>>(s2, cnt, ccol, cval, b2, W3, s3);
    tail_kernel<<<(NN * 8) / 256, 256, 0, stream>>>(s3, cnt, ccol, cval, b3,
                                                    Wlin, blin, outp);
}